// Round 2
// baseline (538.326 us; speedup 1.0000x reference)
//
#include <hip/hip_runtime.h>
#include <cstdint>

#define BB 8
#define CC 128
#define HH 96
#define WW 160
#define HWsz (HH * WW)                    // 15360
#define TH 8
#define TW 32
#define CSTEP 8
#define HALO_H (TH + 8)                   // 16
#define HALO_W (TW + 8)                   // 40
#define CH_WORDS (HALO_H * HALO_W)        // 640
#define CHUNK_WORDS (CSTEP * CH_WORDS)    // 5120 words = 20 KB
#define NWAVES 9
#define NTHREADS (NWAVES * 64)            // 576
#define NCHUNKS (CC / CSTEP)              // 16
#define NBLOCKS (BB * (HH / TH) * (WW / TW))  // 480
#define NSLOTS (CHUNK_WORDS / 256)        // 20 x4-wave-loads per chunk

__device__ __forceinline__ void g2l16(const float* g, float* l) {
  __builtin_amdgcn_global_load_lds((const __attribute__((address_space(1))) void*)g,
                                   (__attribute__((address_space(3))) void*)l,
                                   16, 0, 0);
}

extern "C" __global__ void __launch_bounds__(NTHREADS, 5)
corr81_kernel(const float* __restrict__ x1, const float* __restrict__ x2,
              float* __restrict__ out)
{
  // two DISTINCT shared objects so the compiler can prove ds_read(bufA) does
  // not alias the in-flight global_load_lds writes into bufB (no spurious
  // vmcnt(0) before compute).
  __shared__ __align__(16) float ldsA[CHUNK_WORDS];
  __shared__ __align__(16) float ldsB[CHUNK_WORDS];

  const int tid  = threadIdx.x;
  const int wv   = tid >> 6;     // dy index 0..8 (wave-uniform)
  const int lane = tid & 63;
  const int r    = lane >> 3;    // tile row 0..7
  const int j    = lane & 7;     // w-slot 0..7 (4 px each)

  const int bid = blockIdx.x;
  const int wt  = bid % (WW / TW);
  const int ht  = (bid / (WW / TW)) % (HH / TH);
  const int b   = bid / ((WW / TW) * (HH / TH));
  const int h0  = ht * TH;
  const int w0  = wt * TW;

  // --- staging plan: 20 wave-slots of 64 lanes x 16 B. Wave wv owns slots
  // {wv, wv+9} and (18+wv) if wv<2. Offsets are chunk-invariant (only the
  // channel base advances). Rows are replicate-clamped here; columns are
  // clamped only at segment granularity (register fixup handles replicate).
  const int nslot = (wv < 2) ? 3 : 2;
  int slot_id[3] = {wv, wv + 9, 18 + wv};
  uint32_t goff[3];   // word offset: ci*HW + gh*W + gw (ci = channel within chunk)
  uint32_t lbase[3];  // word offset into the LDS chunk buffer (wave-uniform)
#pragma unroll
  for (int i = 0; i < 3; ++i) {
    const int s   = slot_id[i];
    const int e4  = s * 256 + lane * 4;       // first of 4 words this lane fills
    const int ci  = e4 / CH_WORDS;
    const int rem = e4 - ci * CH_WORDS;
    const int hr  = rem / HALO_W;             // halo row 0..15
    const int seg = (rem - hr * HALO_W) >> 2; // 4-word segment 0..9
    int gh = h0 + hr - 4; gh = gh < 0 ? 0 : (gh > HH - 1 ? HH - 1 : gh);
    int gw = w0 + seg * 4 - 4;
    gw = gw < 0 ? 0 : (gw > WW - 4 ? WW - 4 : gw);   // segment-start clamp only
    goff[i]  = (uint32_t)(ci * HWsz + gh * WW + gw);
    lbase[i] = (uint32_t)(s * 256);
  }

  const float* x2b = x2 + (size_t)b * CC * HWsz;
  const float* x1b = x1 + (size_t)b * CC * HWsz + (size_t)(h0 + r) * WW + (w0 + 4 * j);

  float acc[9][4];
#pragma unroll
  for (int dx = 0; dx < 9; ++dx)
#pragma unroll
    for (int p = 0; p < 4; ++p) acc[dx][p] = 0.f;

  const int rowbase = (r + wv) * HALO_W + 4 * j;  // this thread's window row base
  const bool ledge = (w0 == 0);
  const bool redge = (w0 == WW - TW);

  auto stage = [&](int chunk, float* buf) {
    const float* src = x2b + (size_t)chunk * (CSTEP * HWsz);
#pragma unroll
    for (int i = 0; i < 3; ++i)
      if (i < nslot)                         // wave-uniform predicate
        g2l16(src + goff[i], buf + lbase[i]);
  };

  auto compute = [&](int chunk, const float* buf) {
#pragma unroll
    for (int ci = 0; ci < CSTEP; ++ci) {
      const float4 a4 = *(const float4*)(x1b + (size_t)(chunk * CSTEP + ci) * HWsz);
      const float av[4] = {a4.x, a4.y, a4.z, a4.w};
      const float* wp = buf + ci * CH_WORDS + rowbase;
      const float4 f0 = *(const float4*)(wp);
      const float4 f1 = *(const float4*)(wp + 4);
      const float4 f2 = *(const float4*)(wp + 8);
      float w12[12] = {f0.x, f0.y, f0.z, f0.w,
                       f1.x, f1.y, f1.z, f1.w,
                       f2.x, f2.y, f2.z, f2.w};
      if (ledge) {             // block-uniform -> scalar branch on interior blocks
        if (j == 0) { w12[0] = w12[4]; w12[1] = w12[4]; w12[2] = w12[4]; w12[3] = w12[4]; }
      }
      if (redge) {
        if (j == 7) { w12[8] = w12[7]; w12[9] = w12[7]; w12[10] = w12[7]; w12[11] = w12[7]; }
      }
#pragma unroll
      for (int dx = 0; dx < 9; ++dx)
#pragma unroll
        for (int p = 0; p < 4; ++p)
          acc[dx][p] = fmaf(av[p], w12[dx + p], acc[dx][p]);
    }
  };

  // --- software-pipelined main loop: stage(k+1) issued BEFORE compute(k);
  // the barrier's vmcnt(0) drain is covered by the compute phase.
  stage(0, ldsA);
  __syncthreads();
  for (int chunk = 0; chunk < NCHUNKS; chunk += 2) {
    stage(chunk + 1, ldsB);          // chunk+1 <= 15 always valid (NCHUNKS even)
    compute(chunk, ldsA);
    __syncthreads();
    if (chunk + 2 < NCHUNKS) stage(chunk + 2, ldsA);
    compute(chunk + 1, ldsB);
    __syncthreads();
  }

  // epilogue: out[((b*81 + wv*9+dx)*H + h0+r)*W + w0+4j ...], scale 1/8
  float* op = out + (((size_t)b * 81 + (size_t)wv * 9) * HH + (h0 + r)) * WW + (w0 + 4 * j);
#pragma unroll
  for (int dx = 0; dx < 9; ++dx) {
    float4 v;
    v.x = acc[dx][0] * 0.125f;
    v.y = acc[dx][1] * 0.125f;
    v.z = acc[dx][2] * 0.125f;
    v.w = acc[dx][3] * 0.125f;
    *(float4*)(op + (size_t)dx * HWsz) = v;
  }
}

extern "C" void kernel_launch(void* const* d_in, const int* in_sizes, int n_in,
                              void* d_out, int out_size, void* d_ws, size_t ws_size,
                              hipStream_t stream) {
  const float* x1 = (const float*)d_in[0];
  const float* x2 = (const float*)d_in[1];
  float* out = (float*)d_out;
  corr81_kernel<<<dim3(NBLOCKS), dim3(NTHREADS), 0, stream>>>(x1, x2, out);
}